// Round 14
// baseline (2235.067 us; speedup 1.0000x reference)
//
#include <hip/hip_runtime.h>
#include <cstdint>

// MyRNN: out[b,t,:] = h_t where h_t = tanh(x[b,t,:]@W_xh + b_h + h_{t-1}@W_hh)
// B=64, S=512, D_IN=D_H=1024, fp32 I/O; internal bf16 MFMA.
//
// Round 14: fragment-major h exchange (HX layout). h stored as 16B MFMA
// A-fragment chunks: HX[bg][kk*64 + lane] = H[row=lane&15][kk*32+(lane>>4)*8].
// Consumer waves load their fragments DIRECTLY from MALL with 32 coalesced
// 1KB dwordx4 loads (no LDS, no __syncthreads in the whole RNN loop),
// overlapped with MFMA via counted vmcnt(16)/vmcnt(0).
// Sync protocol = R13 (best measured): per-wave RMW arrival on 4 lines/bg,
// 4-scalar-load poll + s_sleep(1), xp prefetch under the poll.
// OUT stores are plain cacheable (L2 ack, hidden under the h MALL drain).

#define DIN 1024
#define DH  1024
#define NB  64
#define NS  512
#define SPIN_CAP (1u << 20)

typedef __attribute__((ext_vector_type(8))) unsigned short us8;
typedef __attribute__((ext_vector_type(8))) __bf16 bf8;
typedef __attribute__((ext_vector_type(4))) float f32x4;

__device__ __forceinline__ unsigned short f32_bf16(float f) {
  unsigned u = __float_as_uint(f);
  u = (u + 0x7fffu + ((u >> 16) & 1u)) >> 16;
  return (unsigned short)u;
}
__device__ __forceinline__ float bf16_f32(unsigned short h) {
  return __uint_as_float(((unsigned)h) << 16);
}
__device__ __forceinline__ bf8 as_bf8(us8 v) { return __builtin_bit_cast(bf8, v); }

// 16B load with coherent-point bypass (sc0 sc1). Caller must s_waitcnt.
__device__ __forceinline__ us8 load_sc16(const us8* p) {
  us8 r;
  asm volatile("global_load_dwordx4 %0, %1, off sc0 sc1"
               : "=v"(r) : "v"(p) : "memory");
  return r;
}

// ---------------------------------------------------------------- transpose
__global__ __launch_bounds__(256) void k_transpose_bf16(
    const float* __restrict__ W, unsigned short* __restrict__ WT) {
  __shared__ float tile[32][33];
  const int b  = blockIdx.x;
  const int bn = (b & 31) * 32;
  const int bk = (b >> 5) * 32;
  const int tx = threadIdx.x & 31, ty = threadIdx.x >> 5;
#pragma unroll
  for (int i = 0; i < 4; ++i)
    tile[ty + i * 8][tx] = W[(size_t)(bk + ty + i * 8) * DH + bn + tx];
  __syncthreads();
#pragma unroll
  for (int i = 0; i < 4; ++i)
    WT[(size_t)(bn + ty + i * 8) * DIN + bk + tx] = f32_bf16(tile[tx][ty + i * 8]);
}

// ---------------------------------------------------------------- phase 1
__device__ __forceinline__ int lds_idx(int row, int slot) {  // ushort units
  return row * 32 + ((slot ^ ((row >> 1) & 3)) << 3);
}

__global__ __launch_bounds__(256) void k_xproj(
    const float* __restrict__ X,             // [B*S][DIN] fp32
    const unsigned short* __restrict__ WT,   // W_xh^T bf16 [n][k]
    unsigned short* __restrict__ XP) {       // bf16 [s][b][h]
  __shared__ unsigned short As[128 * 32];
  __shared__ unsigned short Bs[128 * 32];
  const int tid = threadIdx.x;
  const int m0 = (int)(blockIdx.x >> 3) * 128;
  const int n0 = (int)(blockIdx.x & 7) * 128;
  const int w = tid >> 6, lane = tid & 63;
  const int wm = (w >> 1) * 64, wn = (w & 1) * 64;
  const int l15 = lane & 15, lhi = lane >> 4;
  const int srow = tid >> 1;
  const int s0 = (tid & 1) * 2;
  f32x4 acc[4][4] = {};

  for (int k0 = 0; k0 < DIN; k0 += 32) {
    const float4* ga = reinterpret_cast<const float4*>(
        X + (size_t)(m0 + srow) * DIN + k0 + s0 * 8);
    float4 f0 = ga[0], f1 = ga[1], f2 = ga[2], f3 = ga[3];
    us8 v0, v1;
    v0[0] = f32_bf16(f0.x); v0[1] = f32_bf16(f0.y); v0[2] = f32_bf16(f0.z); v0[3] = f32_bf16(f0.w);
    v0[4] = f32_bf16(f1.x); v0[5] = f32_bf16(f1.y); v0[6] = f32_bf16(f1.z); v0[7] = f32_bf16(f1.w);
    v1[0] = f32_bf16(f2.x); v1[1] = f32_bf16(f2.y); v1[2] = f32_bf16(f2.z); v1[3] = f32_bf16(f2.w);
    v1[4] = f32_bf16(f3.x); v1[5] = f32_bf16(f3.y); v1[6] = f32_bf16(f3.z); v1[7] = f32_bf16(f3.w);
    *(us8*)&As[lds_idx(srow, s0)]     = v0;
    *(us8*)&As[lds_idx(srow, s0 + 1)] = v1;
    const unsigned short* gb = WT + (size_t)(n0 + srow) * DIN + k0 + s0 * 8;
    *(us8*)&Bs[lds_idx(srow, s0)]     = *reinterpret_cast<const us8*>(gb);
    *(us8*)&Bs[lds_idx(srow, s0 + 1)] = *reinterpret_cast<const us8*>(gb + 8);
    __syncthreads();

    bf8 af[4], bfr[4];
#pragma unroll
    for (int i = 0; i < 4; ++i)
      af[i] = as_bf8(*(const us8*)&As[lds_idx(wm + i * 16 + l15, lhi)]);
#pragma unroll
    for (int r = 0; r < 4; ++r)
      bfr[r] = as_bf8(*(const us8*)&Bs[lds_idx(wn + r * 16 + l15, lhi)]);
#pragma unroll
    for (int i = 0; i < 4; ++i)
#pragma unroll
      for (int r = 0; r < 4; ++r)
        acc[i][r] = __builtin_amdgcn_mfma_f32_16x16x32_bf16(af[i], bfr[r], acc[i][r], 0, 0, 0);
    __syncthreads();
  }
#pragma unroll
  for (int i = 0; i < 4; ++i)
#pragma unroll
    for (int r = 0; r < 4; ++r)
#pragma unroll
      for (int j = 0; j < 4; ++j) {
        int gm = m0 + wm + i * 16 + lhi * 4 + j;
        int gn = n0 + wn + r * 16 + l15;
        int orow = ((gm & 511) << 6) | (gm >> 9);
        XP[(size_t)orow * DH + gn] = f32_bf16(acc[i][r][j]);
      }
}

// ---------------------------------------------------------------- phase 2
// 64 WGs x 256 thr. WG g: bg=g>>4 (rows bg*16..+16), ng=g&15; wave w owns
// cols ng*64+w*16..+16. W_hh^T slice resident in 128 VGPRs/wave.
// HX exchange buffer: 2 parities x 4 bgs x 2048 16B-chunks; chunk
// kk*64 + lane = A-fragment (row=lane&15, k=kk*32+(lane>>4)*8) of bg's tile.
// Consumer: 32 coalesced 1KB loads; vmcnt(16) -> MFMA 0..15 -> vmcnt(0) ->
// MFMA 16..31. NO LDS, NO barriers in the loop.
__global__ __launch_bounds__(256) void k_rnn(
    const unsigned short* __restrict__ WT,  // W_hh^T bf16 [n][k]
    const unsigned short* __restrict__ XP,  // bf16 [s][b][h]
    const float* __restrict__ BH,           // b_h fp32
    float* __restrict__ OUT,                // fp32 [b][s][h]
    unsigned short* __restrict__ HX,        // 2 x 4 x 16K ushort (frag-major)
    unsigned int* __restrict__ ctr) {       // 4 bg x 4 wave lines, 256B apart
  const int tid = threadIdx.x, g = blockIdx.x;
  const int w = tid >> 6, lane = tid & 63;
  const int bg = g >> 4, ng = g & 15;
  const int nbase = ng * 64 + w * 16;
  const int rowbase = bg * 16;
  const int l15 = lane & 15, lhi = lane >> 4;
  const int crow = lhi * 4;

  // preload W_hh^T fragments: 32 x 16B per lane = 128 VGPRs
  bf8 bw[32];
  const unsigned short* wp = WT + (size_t)(nbase + l15) * DIN + lhi * 8;
#pragma unroll
  for (int kk = 0; kk < 32; ++kk)
    bw[kk] = as_bf8(*reinterpret_cast<const us8*>(wp + kk * 32));

  const float bh = BH[nbase + l15];
  unsigned int* arr = &ctr[(bg * 4 + w) * 64];   // this wave's arrival line
  unsigned int* p0 = &ctr[(bg * 4 + 0) * 64];
  unsigned int* p1 = &ctr[(bg * 4 + 1) * 64];
  unsigned int* p2 = &ctr[(bg * 4 + 2) * 64];
  unsigned int* p3 = &ctr[(bg * 4 + 3) * 64];

  // producer HX index: element (r=crow+j, c=nbase+l15) ->
  // ushort idx = ((c>>5)*64 + ((c>>3)&3)*16 + r)*8 + (c&7)
  const int c = nbase + l15;
  const int hxbase = (((c >> 5) * 64 + (((c >> 3) & 3) * 16) + crow) << 3) + (c & 7);

  // prefetch xp for t=0
  float xq[4];
#pragma unroll
  for (int j = 0; j < 4; ++j)
    xq[j] = bf16_f32(XP[(size_t)(rowbase + crow + j) * DH + nbase + l15]);

  float v[4] = {0.f, 0.f, 0.f, 0.f};

#pragma unroll 1
  for (int t = 0; t < NS; ++t) {
    const int pb = t & 1;
    f32x4 a0 = {}, a1 = {}, a2 = {}, a3 = {};
    if (t > 0) {
      // ---- 32 coalesced fragment loads straight from MALL ----
      const us8* hp = reinterpret_cast<const us8*>(HX) +
                      (size_t)pb * 8192 + bg * 2048 + lane;
      us8 hv[32];
#pragma unroll
      for (int kk = 0; kk < 32; ++kk) hv[kk] = load_sc16(hp + kk * 64);
      asm volatile("s_waitcnt vmcnt(16)" ::: "memory");
      __builtin_amdgcn_sched_barrier(0);  // MFMA must not hoist above the wait
#pragma unroll
      for (int kk = 0; kk < 16; kk += 4) {
        a0 = __builtin_amdgcn_mfma_f32_16x16x32_bf16(as_bf8(hv[kk]),     bw[kk],     a0, 0, 0, 0);
        a1 = __builtin_amdgcn_mfma_f32_16x16x32_bf16(as_bf8(hv[kk + 1]), bw[kk + 1], a1, 0, 0, 0);
        a2 = __builtin_amdgcn_mfma_f32_16x16x32_bf16(as_bf8(hv[kk + 2]), bw[kk + 2], a2, 0, 0, 0);
        a3 = __builtin_amdgcn_mfma_f32_16x16x32_bf16(as_bf8(hv[kk + 3]), bw[kk + 3], a3, 0, 0, 0);
      }
      asm volatile("s_waitcnt vmcnt(0)" ::: "memory");
      __builtin_amdgcn_sched_barrier(0);
#pragma unroll
      for (int kk = 16; kk < 32; kk += 4) {
        a0 = __builtin_amdgcn_mfma_f32_16x16x32_bf16(as_bf8(hv[kk]),     bw[kk],     a0, 0, 0, 0);
        a1 = __builtin_amdgcn_mfma_f32_16x16x32_bf16(as_bf8(hv[kk + 1]), bw[kk + 1], a1, 0, 0, 0);
        a2 = __builtin_amdgcn_mfma_f32_16x16x32_bf16(as_bf8(hv[kk + 2]), bw[kk + 2], a2, 0, 0, 0);
        a3 = __builtin_amdgcn_mfma_f32_16x16x32_bf16(as_bf8(hv[kk + 3]), bw[kk + 3], a3, 0, 0, 0);
      }
    }
    f32x4 s = (a0 + a1) + (a2 + a3);

#pragma unroll
    for (int j = 0; j < 4; ++j) {
      float x = xq[j] + s[j] + bh;
      float e = __expf(-2.f * fabsf(x));
      float r = __fdividef(1.f - e, 1.f + e);
      v[j] = copysignf(r, x);
    }

    if (t < NS - 1) {
      // h stores into fragment-major HX (coherent point)
      unsigned short* hx = HX + (size_t)(pb ^ 1) * 65536 + bg * 16384;
#pragma unroll
      for (int j = 0; j < 4; ++j)
        __hip_atomic_store(&hx[hxbase + j * 8], f32_bf16(v[j]),
                           __ATOMIC_RELAXED, __HIP_MEMORY_SCOPE_AGENT);
      // OUT stores for step t: plain cacheable (L2 ack, hidden by h drain)
#pragma unroll
      for (int j = 0; j < 4; ++j)
        OUT[((size_t)(rowbase + crow + j) * NS + t) * DH + nbase + l15] = v[j];
      asm volatile("s_waitcnt vmcnt(0)" ::: "memory");  // drain h (and OUT)
      if (lane == 0)  // per-wave arrival on this wave's own line
        __hip_atomic_fetch_add(arr, 1u, __ATOMIC_RELAXED, __HIP_MEMORY_SCOPE_AGENT);
      // xp prefetch rides under the poll
#pragma unroll
      for (int j = 0; j < 4; ++j)
        xq[j] = bf16_f32(XP[(size_t)(((t + 1) << 6) + rowbase + crow + j) * DH +
                            nbase + l15]);
      const unsigned tgt = 16u * (unsigned)(t + 1);
      for (unsigned it = 0;; ++it) {
        unsigned u0 = __hip_atomic_load(p0, __ATOMIC_RELAXED, __HIP_MEMORY_SCOPE_AGENT);
        unsigned u1 = __hip_atomic_load(p1, __ATOMIC_RELAXED, __HIP_MEMORY_SCOPE_AGENT);
        unsigned u2 = __hip_atomic_load(p2, __ATOMIC_RELAXED, __HIP_MEMORY_SCOPE_AGENT);
        unsigned u3 = __hip_atomic_load(p3, __ATOMIC_RELAXED, __HIP_MEMORY_SCOPE_AGENT);
        if ((u0 >= tgt) & (u1 >= tgt) & (u2 >= tgt) & (u3 >= tgt)) break;
        if (it > SPIN_CAP) break;  // safety: fail fast rather than hang
        __builtin_amdgcn_s_sleep(1);
      }
      asm volatile("" ::: "memory");  // no next-step load hoist above the poll
    } else {
#pragma unroll
      for (int j = 0; j < 4; ++j)
        OUT[((size_t)(rowbase + crow + j) * NS + t) * DH + nbase + l15] = v[j];
    }
  }
}

// ---------------------------------------------------------------- launcher
extern "C" void kernel_launch(void* const* d_in, const int* in_sizes, int n_in,
                              void* d_out, int out_size, void* d_ws, size_t ws_size,
                              hipStream_t stream) {
  (void)in_sizes; (void)n_in; (void)out_size; (void)ws_size;
  const float* X   = (const float*)d_in[0];
  const float* Wxh = (const float*)d_in[1];
  const float* Whh = (const float*)d_in[2];
  const float* bh  = (const float*)d_in[3];
  float* out = (float*)d_out;

  char* ws = (char*)d_ws;
  // layout: wxh_t 2MB | whh_t 2MB | HX 256KB | ctr 4KB | xp 64MB (@4.5MB)
  unsigned short* wxh_t = (unsigned short*)(ws);
  unsigned short* whh_t = (unsigned short*)(ws + 2097152ull);
  unsigned short* hx    = (unsigned short*)(ws + 4194304ull);
  unsigned int*   ctr   = (unsigned int*)(ws + 4456448ull);
  unsigned short* xp    = (unsigned short*)(ws + 4718592ull);

  (void)hipMemsetAsync(ctr, 0, 4096, stream);  // counters start at 0 each call
  k_transpose_bf16<<<1024, 256, 0, stream>>>(Wxh, wxh_t);
  k_transpose_bf16<<<1024, 256, 0, stream>>>(Whh, whh_t);
  k_xproj<<<2048, 256, 0, stream>>>(X, wxh_t, xp);
  k_rnn<<<64, 256, 0, stream>>>(whh_t, xp, bh, out, hx, ctr);
}

// Round 15
// 1255.024 us; speedup vs baseline: 1.7809x; 1.7809x over previous
//
#include <hip/hip_runtime.h>
#include <cstdint>

// MyRNN: out[b,t,:] = h_t where h_t = tanh(x[b,t,:]@W_xh + b_h + h_{t-1}@W_hh)
// B=64, S=512, D_IN=D_H=1024, fp32 I/O; internal bf16 MFMA.
//
// Round 15: SELF-VALIDATING h exchange. Each stored bf16 h value carries a
// 2-bit generation tag in its mantissa LSBs (gen = (step>>1)&3). Producers
// fire-and-forget (no drain, no arrival, no flags, no poll). Consumers'
// staging loads ARE the sync: reload until every dword's tag matches.
// Collapses the per-step chain from ~3 MALL RTs to ~1.
//  - quantization cost of 2 LSBs: ~1e-3 on the recurrence (threshold 1.9e-2)
//  - skew bound <1 generation by data dependence (producers are consumers)
//  - H memset to 0xFF per call kills cross-replay staleness (tag=3 != 0,1)
// Everything else = R13 (best: 1404us): XOR-swizzled LDS staging, W in VGPRs,
// OUT stores post-barrier, xp prefetch after h stores.

#define DIN 1024
#define DH  1024
#define NB  64
#define NS  512
#define SPIN_CAP (1u << 20)

typedef __attribute__((ext_vector_type(8))) unsigned short us8;
typedef __attribute__((ext_vector_type(8))) __bf16 bf8;
typedef __attribute__((ext_vector_type(4))) float f32x4;
typedef __attribute__((ext_vector_type(4))) unsigned int u32x4;

__device__ __forceinline__ unsigned short f32_bf16(float f) {
  unsigned u = __float_as_uint(f);
  u = (u + 0x7fffu + ((u >> 16) & 1u)) >> 16;
  return (unsigned short)u;
}
__device__ __forceinline__ float bf16_f32(unsigned short h) {
  return __uint_as_float(((unsigned)h) << 16);
}
__device__ __forceinline__ bf8 as_bf8(us8 v) { return __builtin_bit_cast(bf8, v); }

// 16B load with coherent-point bypass (sc0 sc1). Caller must s_waitcnt.
__device__ __forceinline__ us8 load_sc16(const us8* p) {
  us8 r;
  asm volatile("global_load_dwordx4 %0, %1, off sc0 sc1"
               : "=v"(r) : "v"(p) : "memory");
  return r;
}

// ---------------------------------------------------------------- transpose
__global__ __launch_bounds__(256) void k_transpose_bf16(
    const float* __restrict__ W, unsigned short* __restrict__ WT) {
  __shared__ float tile[32][33];
  const int b  = blockIdx.x;
  const int bn = (b & 31) * 32;
  const int bk = (b >> 5) * 32;
  const int tx = threadIdx.x & 31, ty = threadIdx.x >> 5;
#pragma unroll
  for (int i = 0; i < 4; ++i)
    tile[ty + i * 8][tx] = W[(size_t)(bk + ty + i * 8) * DH + bn + tx];
  __syncthreads();
#pragma unroll
  for (int i = 0; i < 4; ++i)
    WT[(size_t)(bn + ty + i * 8) * DIN + bk + tx] = f32_bf16(tile[tx][ty + i * 8]);
}

// ---------------------------------------------------------------- phase 1
__device__ __forceinline__ int lds_idx(int row, int slot) {  // ushort units
  return row * 32 + ((slot ^ ((row >> 1) & 3)) << 3);
}

__global__ __launch_bounds__(256) void k_xproj(
    const float* __restrict__ X,             // [B*S][DIN] fp32
    const unsigned short* __restrict__ WT,   // W_xh^T bf16 [n][k]
    unsigned short* __restrict__ XP) {       // bf16 [s][b][h]
  __shared__ unsigned short As[128 * 32];
  __shared__ unsigned short Bs[128 * 32];
  const int tid = threadIdx.x;
  const int m0 = (int)(blockIdx.x >> 3) * 128;
  const int n0 = (int)(blockIdx.x & 7) * 128;
  const int w = tid >> 6, lane = tid & 63;
  const int wm = (w >> 1) * 64, wn = (w & 1) * 64;
  const int l15 = lane & 15, lhi = lane >> 4;
  const int srow = tid >> 1;
  const int s0 = (tid & 1) * 2;
  f32x4 acc[4][4] = {};

  for (int k0 = 0; k0 < DIN; k0 += 32) {
    const float4* ga = reinterpret_cast<const float4*>(
        X + (size_t)(m0 + srow) * DIN + k0 + s0 * 8);
    float4 f0 = ga[0], f1 = ga[1], f2 = ga[2], f3 = ga[3];
    us8 v0, v1;
    v0[0] = f32_bf16(f0.x); v0[1] = f32_bf16(f0.y); v0[2] = f32_bf16(f0.z); v0[3] = f32_bf16(f0.w);
    v0[4] = f32_bf16(f1.x); v0[5] = f32_bf16(f1.y); v0[6] = f32_bf16(f1.z); v0[7] = f32_bf16(f1.w);
    v1[0] = f32_bf16(f2.x); v1[1] = f32_bf16(f2.y); v1[2] = f32_bf16(f2.z); v1[3] = f32_bf16(f2.w);
    v1[4] = f32_bf16(f3.x); v1[5] = f32_bf16(f3.y); v1[6] = f32_bf16(f3.z); v1[7] = f32_bf16(f3.w);
    *(us8*)&As[lds_idx(srow, s0)]     = v0;
    *(us8*)&As[lds_idx(srow, s0 + 1)] = v1;
    const unsigned short* gb = WT + (size_t)(n0 + srow) * DIN + k0 + s0 * 8;
    *(us8*)&Bs[lds_idx(srow, s0)]     = *reinterpret_cast<const us8*>(gb);
    *(us8*)&Bs[lds_idx(srow, s0 + 1)] = *reinterpret_cast<const us8*>(gb + 8);
    __syncthreads();

    bf8 af[4], bfr[4];
#pragma unroll
    for (int i = 0; i < 4; ++i)
      af[i] = as_bf8(*(const us8*)&As[lds_idx(wm + i * 16 + l15, lhi)]);
#pragma unroll
    for (int r = 0; r < 4; ++r)
      bfr[r] = as_bf8(*(const us8*)&Bs[lds_idx(wn + r * 16 + l15, lhi)]);
#pragma unroll
    for (int i = 0; i < 4; ++i)
#pragma unroll
      for (int r = 0; r < 4; ++r)
        acc[i][r] = __builtin_amdgcn_mfma_f32_16x16x32_bf16(af[i], bfr[r], acc[i][r], 0, 0, 0);
    __syncthreads();
  }
#pragma unroll
  for (int i = 0; i < 4; ++i)
#pragma unroll
    for (int r = 0; r < 4; ++r)
#pragma unroll
      for (int j = 0; j < 4; ++j) {
        int gm = m0 + wm + i * 16 + lhi * 4 + j;
        int gn = n0 + wn + r * 16 + l15;
        int orow = ((gm & 511) << 6) | (gm >> 9);
        XP[(size_t)orow * DH + gn] = f32_bf16(acc[i][r][j]);
      }
}

// ---------------------------------------------------------------- phase 2
// 64 WGs x 256 thr. WG g: bg=g>>4 (rows bg*16..+16), ng=g&15; wave w owns
// cols ng*64+w*16..+16. W_hh^T slice resident in 128 VGPRs/wave.
// h exchange: H = 2 x [64][1024] bf16, every element's 2 mantissa LSBs hold
// gen=(consumer_step>>1)&3. Consumer stages 8x16B chunks per thread, reloads
// until all tags match, writes XOR-swizzled LDS, one barrier, 32 MFMA.
// Producers fire-and-forget. NO flags, NO drain, NO poll.
__global__ __launch_bounds__(256) void k_rnn(
    const unsigned short* __restrict__ WT,  // W_hh^T bf16 [n][k]
    const unsigned short* __restrict__ XP,  // bf16 [s][b][h]
    const float* __restrict__ BH,           // b_h fp32
    float* __restrict__ OUT,                // fp32 [b][s][h]
    unsigned short* __restrict__ H) {       // 2 x [NB][DH] bf16 (0xFF memset)
  __shared__ us8 hs[2][2048];               // 2 x 32KB
  const int tid = threadIdx.x, g = blockIdx.x;
  const int w = tid >> 6, lane = tid & 63;
  const int bg = g >> 4, ng = g & 15;
  const int nbase = ng * 64 + w * 16;
  const int rowbase = bg * 16;
  const int l15 = lane & 15, lhi = lane >> 4;
  const int crow = lhi * 4;
  const int th = tid >> 7;                  // staging row parity
  const int c7 = tid & 127;                 // staging chunk-in-row
  const int rbase = l15 * 128;              // read: row base (16B slots)
  const int rx = l15 & 7;                   // read: XOR key

  // preload W_hh^T fragments: 32 x 16B per lane = 128 VGPRs
  bf8 bw[32];
  const unsigned short* wp = WT + (size_t)(nbase + l15) * DIN + lhi * 8;
#pragma unroll
  for (int kk = 0; kk < 32; ++kk)
    bw[kk] = as_bf8(*reinterpret_cast<const us8*>(wp + kk * 32));

  const float bh = BH[nbase + l15];

  // prefetch xp for t=0
  float xq[4];
#pragma unroll
  for (int j = 0; j < 4; ++j)
    xq[j] = bf16_f32(XP[(size_t)(rowbase + crow + j) * DH + nbase + l15]);

  float v[4] = {0.f, 0.f, 0.f, 0.f};

#pragma unroll 1
  for (int t = 0; t < NS; ++t) {
    const int pb = t & 1;
    f32x4 a0 = {}, a1 = {}, a2 = {}, a3 = {};
    if (t > 0) {
      // ---- stage h[pb] with tag validation: the load IS the sync ----
      const us8* hg = reinterpret_cast<const us8*>(H) +
                      (size_t)pb * 8192 + rowbase * 128 + tid;
      const unsigned g2 = (unsigned)((t >> 1) & 3);
      const unsigned pat = g2 * 0x00010001u;
      us8 hv[8];
      for (unsigned it = 0;; ++it) {
#pragma unroll
        for (int i = 0; i < 8; ++i) hv[i] = load_sc16(hg + 256 * i);
        asm volatile("s_waitcnt vmcnt(0)" ::: "memory");
        __builtin_amdgcn_sched_barrier(0);
        unsigned bad = 0;
#pragma unroll
        for (int i = 0; i < 8; ++i) {
          u32x4 dv = __builtin_bit_cast(u32x4, hv[i]);
          bad |= (dv.x ^ pat) & 0x00030003u;
          bad |= (dv.y ^ pat) & 0x00030003u;
          bad |= (dv.z ^ pat) & 0x00030003u;
          bad |= (dv.w ^ pat) & 0x00030003u;
        }
        if (__all(bad == 0u)) break;
        if (it > SPIN_CAP) break;  // fail fast, never hang
        __builtin_amdgcn_s_sleep(1);
      }
#pragma unroll
      for (int i = 0; i < 8; ++i) {
        const int r = 2 * i + th;
        hs[pb][r * 128 + (c7 ^ (r & 7))] = hv[i];
      }
      __syncthreads();  // the ONLY barrier per step
      // ---- OUT stores for t-1: acks drain under MFMA+tanh ----
#pragma unroll
      for (int j = 0; j < 4; ++j)
        __builtin_nontemporal_store(
            v[j],
            &OUT[((size_t)(rowbase + crow + j) * NS + (t - 1)) * DH + nbase + l15]);
      // ---- A-fragment reads + 32 MFMA ----
#pragma unroll
      for (int kk = 0; kk < 32; kk += 4) {
        bf8 h0 = as_bf8(hs[pb][rbase + (((kk + 0) * 4 + lhi) ^ rx)]);
        bf8 h1 = as_bf8(hs[pb][rbase + (((kk + 1) * 4 + lhi) ^ rx)]);
        bf8 h2 = as_bf8(hs[pb][rbase + (((kk + 2) * 4 + lhi) ^ rx)]);
        bf8 h3 = as_bf8(hs[pb][rbase + (((kk + 3) * 4 + lhi) ^ rx)]);
        a0 = __builtin_amdgcn_mfma_f32_16x16x32_bf16(h0, bw[kk],     a0, 0, 0, 0);
        a1 = __builtin_amdgcn_mfma_f32_16x16x32_bf16(h1, bw[kk + 1], a1, 0, 0, 0);
        a2 = __builtin_amdgcn_mfma_f32_16x16x32_bf16(h2, bw[kk + 2], a2, 0, 0, 0);
        a3 = __builtin_amdgcn_mfma_f32_16x16x32_bf16(h3, bw[kk + 3], a3, 0, 0, 0);
      }
    }
    f32x4 s = (a0 + a1) + (a2 + a3);

#pragma unroll
    for (int j = 0; j < 4; ++j) {
      float x = xq[j] + s[j] + bh;
      float e = __expf(-2.f * fabsf(x));
      float r = __fdividef(1.f - e, 1.f + e);
      v[j] = copysignf(r, x);
    }

    if (t < NS - 1) {
      // tagged h stores: fire-and-forget (sync is embedded in the data)
      unsigned short* hnext = H + (size_t)(pb ^ 1) * (NB * DH);
      const unsigned gs = (unsigned)(((t + 1) >> 1) & 3);
#pragma unroll
      for (int j = 0; j < 4; ++j) {
        const unsigned short pv =
            (unsigned short)((f32_bf16(v[j]) & 0xFFFCu) | gs);
        __hip_atomic_store(hnext + (size_t)(rowbase + crow + j) * DH + nbase + l15,
                           pv, __ATOMIC_RELAXED, __HIP_MEMORY_SCOPE_AGENT);
      }
      // xp prefetch for t+1 (completes under next staging's vmcnt)
#pragma unroll
      for (int j = 0; j < 4; ++j)
        xq[j] = bf16_f32(XP[(size_t)(((t + 1) << 6) + rowbase + crow + j) * DH +
                            nbase + l15]);
    }
  }
  // final OUT stores for t = NS-1
#pragma unroll
  for (int j = 0; j < 4; ++j)
    __builtin_nontemporal_store(
        v[j], &OUT[((size_t)(rowbase + crow + j) * NS + (NS - 1)) * DH + nbase + l15]);
}

// ---------------------------------------------------------------- launcher
extern "C" void kernel_launch(void* const* d_in, const int* in_sizes, int n_in,
                              void* d_out, int out_size, void* d_ws, size_t ws_size,
                              hipStream_t stream) {
  (void)in_sizes; (void)n_in; (void)out_size; (void)ws_size;
  const float* X   = (const float*)d_in[0];
  const float* Wxh = (const float*)d_in[1];
  const float* Whh = (const float*)d_in[2];
  const float* bh  = (const float*)d_in[3];
  float* out = (float*)d_out;

  char* ws = (char*)d_ws;
  // layout: wxh_t 2MB | whh_t 2MB | h 256KB | xp 64MB (@4.5MB)
  unsigned short* wxh_t = (unsigned short*)(ws);
  unsigned short* whh_t = (unsigned short*)(ws + 2097152ull);
  unsigned short* hbuf  = (unsigned short*)(ws + 4194304ull);
  unsigned short* xp    = (unsigned short*)(ws + 4718592ull);

  // 0xFF fill => tag bits = 3 everywhere; first reads expect 0/1 => stale
  // data from prior replays can never validate.
  (void)hipMemsetAsync(hbuf, 0xFF, 262144, stream);
  k_transpose_bf16<<<1024, 256, 0, stream>>>(Wxh, wxh_t);
  k_transpose_bf16<<<1024, 256, 0, stream>>>(Whh, whh_t);
  k_xproj<<<2048, 256, 0, stream>>>(X, wxh_t, xp);
  k_rnn<<<64, 256, 0, stream>>>(whh_t, xp, bh, out, hbuf);
}